// Round 6
// baseline (382.579 us; speedup 1.0000x reference)
//
#include <hip/hip_runtime.h>
#include <math.h>

typedef __bf16 bf16_t;
typedef __bf16 bf16x8 __attribute__((ext_vector_type(8)));
typedef __bf16 bf16x4 __attribute__((ext_vector_type(4)));
typedef float f32x4 __attribute__((ext_vector_type(4)));

#define DIM 768
#define NE 4
#define NH 12
#define HD 64
#define MLP_HID 3072
#define FC1_OUT 5376
#define FC2_IN 3840
#define CAP 512
#define LOG2E 1.44269504088896340736f

__device__ __forceinline__ void async_copy16(const void* g, void* l) {
  __builtin_amdgcn_global_load_lds((const __attribute__((address_space(1))) void*)g,
                                   (__attribute__((address_space(3))) void*)l, 16, 0, 0);
}

// sigmoid-form tanh-GELU: gelu(v) = v * rcp(1 + exp2(v*(c1 + c2*v^2)))
// max abs dev from exact-erf gelu ~7e-4 -- invisible at bf16.
__device__ __forceinline__ float gelu_f(float v) {
  float v2 = v * v;
  float t = v * fmaf(-0.102944f, v2, -2.302208f);
  float e = exp2f(t);
  return v * __builtin_amdgcn_rcpf(1.0f + e);
}

// ---------------- fused: weight cast (blocks 0..2047) + router softmax (blocks 2048..4095) ----------------
__global__ __launch_bounds__(256) void cast_router_kernel(const float* __restrict__ w1,
                                                          const float* __restrict__ w2,
                                                          bf16_t* __restrict__ w1b,
                                                          bf16_t* __restrict__ w2b,
                                                          const float* __restrict__ x,
                                                          const float* __restrict__ wr,
                                                          float* __restrict__ probs) {
  if (blockIdx.x < 2048) {
    const int N1 = FC1_OUT * DIM / 4;     // 1032192 float4s
    const int N2 = 1536 * FC2_IN / 4;     // 1474560 float4s
    const float4* w1v = (const float4*)w1;
    const float4* w2v = (const float4*)w2;
    for (int i = blockIdx.x * 256 + threadIdx.x; i < N1 + N2; i += 2048 * 256) {
      float4 f;
      bf16_t* dst;
      if (i < N1) { f = w1v[i]; dst = w1b + (size_t)i * 4; }
      else        { f = w2v[i - N1]; dst = w2b + (size_t)(i - N1) * 4; }
      bf16x4 o;
      o[0] = (bf16_t)f.x; o[1] = (bf16_t)f.y; o[2] = (bf16_t)f.z; o[3] = (bf16_t)f.w;
      *(bf16x4*)dst = o;
    }
    return;
  }
  int t = (blockIdx.x - 2048) * 4 + (threadIdx.x >> 6);
  int l = threadIdx.x & 63;
  const float4* xr = (const float4*)(x + (size_t)t * DIM);
  const float4* wr4 = (const float4*)wr;
  float a0 = 0.f, a1 = 0.f, a2 = 0.f, a3 = 0.f;
#pragma unroll
  for (int i = 0; i < 3; i++) {
    int d4 = l + i * 64;                  // float4 index within row (768/4 = 192)
    float4 xv = xr[d4];
    float4 w0 = wr4[d4];
    float4 w1e = wr4[192 + d4];
    float4 w2e = wr4[384 + d4];
    float4 w3e = wr4[576 + d4];
    a0 += xv.x * w0.x + xv.y * w0.y + xv.z * w0.z + xv.w * w0.w;
    a1 += xv.x * w1e.x + xv.y * w1e.y + xv.z * w1e.z + xv.w * w1e.w;
    a2 += xv.x * w2e.x + xv.y * w2e.y + xv.z * w2e.z + xv.w * w2e.w;
    a3 += xv.x * w3e.x + xv.y * w3e.y + xv.z * w3e.z + xv.w * w3e.w;
  }
#pragma unroll
  for (int off = 32; off > 0; off >>= 1) {
    a0 += __shfl_down(a0, off);
    a1 += __shfl_down(a1, off);
    a2 += __shfl_down(a2, off);
    a3 += __shfl_down(a3, off);
  }
  if (l == 0) {
    float m = fmaxf(fmaxf(a0, a1), fmaxf(a2, a3));
    float e0 = expf(a0 - m), e1 = expf(a1 - m), e2 = expf(a2 - m), e3 = expf(a3 - m);
    float inv = 1.0f / (e0 + e1 + e2 + e3);
    int b = t >> 10, n = t & 1023;
    probs[(b * NE + 0) * 1024 + n] = e0 * inv;
    probs[(b * NE + 1) * 1024 + n] = e1 * inv;
    probs[(b * NE + 2) * 1024 + n] = e2 * inv;
    probs[(b * NE + 3) * 1024 + n] = e3 * inv;
  }
}

// ---------------- exact top-k membership via ranking ----------------
__global__ __launch_bounds__(256) void rank_kernel(const float* __restrict__ probs,
                                                   float* __restrict__ gate_tok) {
  int be = blockIdx.y;
  __shared__ float p[1024];
  for (int i = threadIdx.x; i < 1024; i += 256) p[i] = probs[be * 1024 + i];
  __syncthreads();
  int n = blockIdx.x * 256 + threadIdx.x;
  float pn = p[n];
  int rank = 0;
  for (int j = 0; j < 1024; j++) {
    float pj = p[j];
    rank += (pj > pn) || (pj == pn && j < n);
  }
  int b = be >> 2, e = be & 3;
  gate_tok[(size_t)((b << 10) + n) * 4 + e] = (rank < CAP) ? pn : 0.0f;
}

// ---------------- LayerNorm + segment-count scaling -> bf16; emit gate suffix sums ----------------
__global__ __launch_bounds__(256) void ln_kernel(const float* __restrict__ x,
                                                 const float* __restrict__ gamma,
                                                 const float* __restrict__ beta,
                                                 const float* __restrict__ gate_tok,
                                                 bf16_t* __restrict__ ytil,
                                                 float* __restrict__ cntf,
                                                 float* __restrict__ g4) {
  int t = blockIdx.x * 4 + (threadIdx.x >> 6);
  int l = threadIdx.x & 63;
  float4 gg = ((const float4*)gate_tok)[t];
  float s0 = (gg.x > 0.f) ? 1.f : 0.f;
  float s1 = (gg.y > 0.f) ? 1.f : 0.f;
  float s2 = (gg.z > 0.f) ? 1.f : 0.f;
  float s3 = (gg.w > 0.f) ? 1.f : 0.f;
  float c3 = s3, c2 = c3 + s2, c1 = c2 + s1, c0 = c1 + s0;
  if (l == 0) {
    cntf[t] = c0;
    float4 G;
    G.x = gg.x + gg.y + gg.z + gg.w;
    G.y = gg.y + gg.z + gg.w;
    G.z = gg.z + gg.w;
    G.w = gg.w;
    ((float4*)g4)[t] = G;
  }
  const float4* xr = (const float4*)(x + (size_t)t * DIM);
  const float4* gm4 = (const float4*)gamma;
  const float4* bt4 = (const float4*)beta;
  float4 v[3];
  float s = 0.f, sq = 0.f;
#pragma unroll
  for (int i = 0; i < 3; i++) {
    v[i] = xr[l + i * 64];
    s += v[i].x + v[i].y + v[i].z + v[i].w;
    sq += v[i].x * v[i].x + v[i].y * v[i].y + v[i].z * v[i].z + v[i].w * v[i].w;
  }
#pragma unroll
  for (int off = 1; off < 64; off <<= 1) {
    s += __shfl_xor(s, off);
    sq += __shfl_xor(sq, off);
  }
  float mean = s * (1.0f / DIM);
  float var = sq * (1.0f / DIM) - mean * mean;
  float rs = rsqrtf(var + 1e-6f);
#pragma unroll
  for (int i = 0; i < 3; i++) {
    int d4 = l + i * 64;
    int d0 = d4 * 4;
    float cf = (d0 < 96) ? c0 : (d0 < 192) ? c1 : (d0 < 384) ? c2 : c3;
    float4 gmv = gm4[d4], btv = bt4[d4];
    bf16x4 o;
    o[0] = (bf16_t)(((v[i].x - mean) * rs * gmv.x + btv.x) * cf);
    o[1] = (bf16_t)(((v[i].y - mean) * rs * gmv.y + btv.y) * cf);
    o[2] = (bf16_t)(((v[i].z - mean) * rs * gmv.z + btv.z) * cf);
    o[3] = (bf16_t)(((v[i].w - mean) * rs * gmv.w + btv.w) * cf);
    *(bf16x4*)(ytil + (size_t)t * DIM + d0) = o;
  }
}

// ---------------- FC1 dense: [8192,5376] = ytil @ w1^T + cnt*b1; epilogue gelu / qkv split ----------------
// Q is pre-scaled by 0.125*log2e so attention scores are directly in log2 units.
// vtb (transposed V): token axis permuted within each 64-block by kappa^-1 (tau=32a+16c+4b+d stored
// at column 32a+8b+4c+d) so attn's swapped-QK P-fragments align with V octets with ZERO shuffles.
__global__ __launch_bounds__(256, 4) void fc1_kernel(const bf16_t* __restrict__ ytil,
                                                     const bf16_t* __restrict__ w1b,
                                                     const float* __restrict__ b1,
                                                     const float* __restrict__ cntf,
                                                     bf16_t* __restrict__ y2b,
                                                     bf16_t* __restrict__ qb,
                                                     bf16_t* __restrict__ kb,
                                                     bf16_t* __restrict__ vtb) {
  const int bid = blockIdx.x;
  const int xcd = bid & 7, j = bid >> 3;      // j in 0..335
  const int mt = xcd * 8 + (j & 7);           // 0..63 (fast within XCD)
  const int nt = j >> 3;                      // 0..41 (slow)
  const int tid = threadIdx.x;
  const int w = tid >> 6, l = tid & 63;
  const int lq = l >> 4, lr = l & 15;

  __shared__ __align__(16) bf16_t lA[128 * 64];
  __shared__ __align__(16) bf16_t lB[128 * 64];

  f32x4 acc[4][4] = {};
  const int mwave = (w & 1) * 64, nwave = (w >> 1) * 64;
  const int crow = l >> 3;
  const int cbg = (l & 7) ^ (crow & 7);

  for (int k0 = 0; k0 < DIM; k0 += 64) {
#pragma unroll
    for (int i = 0; i < 4; i++) {
      int c = w * 4 + i;
      int row = c * 8 + crow;
      async_copy16(ytil + (size_t)(mt * 128 + row) * DIM + k0 + cbg * 8, lA + c * 512);
      async_copy16(w1b + (size_t)(nt * 128 + row) * DIM + k0 + cbg * 8, lB + c * 512);
    }
    __syncthreads();
#pragma unroll
    for (int ks = 0; ks < 2; ks++) {
      const int cbA = ((ks * 4 + lq) ^ (lr & 7)) * 8;
      bf16x8 af[4], bfr[4];
#pragma unroll
      for (int mi = 0; mi < 4; mi++)
        af[mi] = *(const bf16x8*)(lA + (mwave + mi * 16 + lr) * 64 + cbA);
#pragma unroll
      for (int ni = 0; ni < 4; ni++)
        bfr[ni] = *(const bf16x8*)(lB + (nwave + ni * 16 + lr) * 64 + cbA);
#pragma unroll
      for (int mi = 0; mi < 4; mi++)
#pragma unroll
        for (int ni = 0; ni < 4; ni++)
          acc[mi][ni] = __builtin_amdgcn_mfma_f32_16x16x32_bf16(af[mi], bfr[ni], acc[mi][ni], 0, 0, 0);
    }
    __syncthreads();
  }

#pragma unroll
  for (int mi = 0; mi < 4; mi++) {
    int row0 = mt * 128 + mwave + mi * 16 + lq * 4;
    float cnt[4];
#pragma unroll
    for (int r = 0; r < 4; r++) cnt[r] = cntf[row0 + r];
#pragma unroll
    for (int ni = 0; ni < 4; ni++) {
      int col = nt * 128 + nwave + ni * 16 + lr;
      float bias = b1[col];
      if (col < MLP_HID) {
#pragma unroll
        for (int r = 0; r < 4; r++) {
          float v = acc[mi][ni][r] + cnt[r] * bias;
          y2b[(size_t)(row0 + r) * FC2_IN + col] = (bf16_t)gelu_f(v);
        }
      } else {
        int part = col - MLP_HID;
        int comp = (part >= 1536) ? 2 : (part >= 768) ? 1 : 0;
        int rem = part - comp * 768;
        int hh = rem >> 6, d = rem & 63;
        int b = row0 >> 10, n0 = row0 & 1023;
        size_t base = (size_t)(b * NH + hh);
        if (comp == 2) {
          bf16x4 pk;
#pragma unroll
          for (int r = 0; r < 4; r++)
            pk[r] = (bf16_t)(acc[mi][ni][r] + cnt[r] * bias);
          // kappa^-1 permutation of token-offset within the 64-block (8B-quad granular):
          // off = 32a+16th+4tm (tl=0)  ->  32a+8tm+4th
          int n0p = (n0 & ~63) | (n0 & 32) | (((n0 >> 2) & 3) << 3) | (((n0 >> 4) & 1) << 2);
          *(bf16x4*)(vtb + (base * HD + d) * 1024 + n0p) = pk;
        } else {
#pragma unroll
          for (int r = 0; r < 4; r++) {
            float v = acc[mi][ni][r] + cnt[r] * bias;
            if (comp == 0) qb[(base * 1024 + n0 + r) * HD + d] = (bf16_t)(v * (0.125f * LOG2E));
            else           kb[(base * 1024 + n0 + r) * HD + d] = (bf16_t)v;
          }
        }
      }
    }
  }
}

// ---------------- flash attention, swapped QK^T, fully in-register softmax ----------------
// sacc^T = mfma(kf, qf): each lane's 16 P-values all belong to ONE q-row (q = qb0+lr); exp2 +
// psum are pure per-lane ops; P packs directly into the PV A-fragment because V's token axis was
// pre-permuted (kappa) at fc1 store time. No lP buffer, no cross-lane traffic in the kt loop.
__global__ __launch_bounds__(256) void attn_kernel(const bf16_t* __restrict__ qb,
                                                   const bf16_t* __restrict__ kb,
                                                   const bf16_t* __restrict__ vtb,
                                                   bf16_t* __restrict__ y2b) {
  const int bid = blockIdx.x;                 // 0..767
  const int xcd = bid & 7, j = bid >> 3;      // j 0..95
  const int bh = xcd * 12 + (j >> 3);         // all 8 q-blocks of a head on one XCD
  const int qt = j & 7;                       // 128-row q tile
  const int tid = threadIdx.x;
  const int w = tid >> 6, l = tid & 63, lq = l >> 4, lr = l & 15;

  __shared__ __align__(16) bf16_t lK[2][64 * 64];
  __shared__ __align__(16) bf16_t lV[2][64 * 64];

  const bf16_t* qbase = qb + (size_t)bh * 1024 * HD;
  const bf16_t* kbase = kb + (size_t)bh * 1024 * HD;
  const bf16_t* vbase = vtb + (size_t)bh * HD * 1024;

  bf16x8 qf[2][2];
#pragma unroll
  for (int h = 0; h < 2; h++) {
    int qrow = qt * 128 + h * 64 + w * 16 + lr;
#pragma unroll
    for (int s = 0; s < 2; s++)
      qf[h][s] = *(const bf16x8*)(qbase + (size_t)qrow * HD + s * 32 + lq * 8);
  }

  f32x4 oacc[2][4] = {};
  float psum[2] = {0.f, 0.f};

  const int crow = l >> 3;
  const int cbg = (l & 7) ^ (crow & 7);

  auto stage = [&](int buf, int kt) {
#pragma unroll
    for (int i = 0; i < 2; i++) {
      int c = w * 2 + i;
      int row = c * 8 + crow;
      async_copy16(kbase + (size_t)(kt * 64 + row) * HD + cbg * 8, &lK[buf][c * 512]);
      async_copy16(vbase + (size_t)row * 1024 + kt * 64 + cbg * 8, &lV[buf][c * 512]);
    }
  };

  stage(0, 0);
  __syncthreads();

  int cur = 0;
  for (int kt = 0; kt < 16; kt++) {
    if (kt + 1 < 16) stage(cur ^ 1, kt + 1);

#pragma unroll
    for (int h = 0; h < 2; h++) {
      f32x4 sacc[4] = {};
#pragma unroll
      for (int s = 0; s < 2; s++) {
        const int cb = ((s * 4 + lq) ^ (lr & 7)) * 8;
#pragma unroll
        for (int kbq = 0; kbq < 4; kbq++) {
          bf16x8 kf = *(const bf16x8*)(&lK[cur][(kbq * 16 + lr) * 64 + cb]);
          sacc[kbq] = __builtin_amdgcn_mfma_f32_16x16x32_bf16(kf, qf[h][s], sacc[kbq], 0, 0, 0);
        }
      }

      // in-register softmax: S^T lane layout = 16 tokens (16kbq+4lq+r) of ONE q-row (qb0+lr)
      float p[4][4];
#pragma unroll
      for (int kbq = 0; kbq < 4; kbq++)
#pragma unroll
        for (int r = 0; r < 4; r++) {
          p[kbq][r] = exp2f(sacc[kbq][r]);
          psum[h] += p[kbq][r];
        }
      bf16x8 pf[2];
#pragma unroll
      for (int ks = 0; ks < 2; ks++)
#pragma unroll
        for (int jj = 0; jj < 8; jj++)
          pf[ks][jj] = (bf16_t)p[2 * ks + (jj >> 2)][jj & 3];

#pragma unroll
      for (int ks = 0; ks < 2; ks++) {
        const int cb = ((ks * 4 + lq) ^ (lr & 7)) * 8;
#pragma unroll
        for (int nb = 0; nb < 4; nb++) {
          bf16x8 vf = *(const bf16x8*)(&lV[cur][(nb * 16 + lr) * 64 + cb]);
          oacc[h][nb] = __builtin_amdgcn_mfma_f32_16x16x32_bf16(pf[ks], vf, oacc[h][nb], 0, 0, 0);
        }
      }
    }
    __syncthreads();
    cur ^= 1;
  }

  int b = bh / NH, hh = bh % NH;
#pragma unroll
  for (int h = 0; h < 2; h++) {
    float ps = psum[h];
    ps += __shfl_xor(ps, 16);
    ps += __shfl_xor(ps, 32);     // full row-sum for q-row (w*16 + lr), uniform across lq
    float rinv[4];
#pragma unroll
    for (int r = 0; r < 4; r++) rinv[r] = 1.0f / __shfl(ps, lq * 4 + r);  // C rows = lq*4+r
#pragma unroll
    for (int nb = 0; nb < 4; nb++)
#pragma unroll
      for (int r = 0; r < 4; r++) {
        float v = oacc[h][nb][r] * rinv[r];
        int tok = qt * 128 + h * 64 + w * 16 + lq * 4 + r;
        y2b[((size_t)(b * 1024 + tok)) * FC2_IN + MLP_HID + hh * HD + nb * 16 + lr] = (bf16_t)v;
      }
  }
}

// ---------------- FC2 dense fused: out = x + Sum_halves G_seg(col) * (y2 @ w2^T + b2) ----------------
// Round-0 proven structure: 128x128 tile, 256 thr, single-buffered LDS, 3 blocks/CU implicit overlap.
__global__ __launch_bounds__(256, 4) void fc2_kernel(const bf16_t* __restrict__ y2b,
                                                     const bf16_t* __restrict__ w2b,
                                                     const float* __restrict__ b2,
                                                     const float* __restrict__ g4,
                                                     const float* __restrict__ x,
                                                     float* __restrict__ out) {
  const int bid = blockIdx.x;
  const int xcd = bid & 7, j = bid >> 3;
  const int mt = xcd * 8 + j / 12;
  const int ct = j % 12;
  const int tid = threadIdx.x;
  const int w = tid >> 6, l = tid & 63;
  const int lq = l >> 4, lr = l & 15;

  __shared__ __align__(16) bf16_t lA[128 * 64];
  __shared__ __align__(16) bf16_t lB[128 * 64];

  f32x4 acc[2][4][2] = {};
  const int mwave = (w & 1) * 64, nwave = (w >> 1) * 32;
  const int crow = l >> 3;
  const int cbg = (l & 7) ^ (crow & 7);

  for (int k0 = 0; k0 < FC2_IN; k0 += 64) {
#pragma unroll
    for (int i = 0; i < 4; i++) {
      int c = w * 4 + i;
      int row = c * 8 + crow;
      async_copy16(y2b + (size_t)(mt * 128 + row) * FC2_IN + k0 + cbg * 8, lA + c * 512);
      int grow = ((row >> 6) * 768) + ct * 64 + (row & 63);
      async_copy16(w2b + (size_t)grow * FC2_IN + k0 + cbg * 8, lB + c * 512);
    }
    __syncthreads();
#pragma unroll
    for (int ks = 0; ks < 2; ks++) {
      const int cbA = ((ks * 4 + lq) ^ (lr & 7)) * 8;
      bf16x8 af[4], bfr[2][2];
#pragma unroll
      for (int mi = 0; mi < 4; mi++)
        af[mi] = *(const bf16x8*)(lA + (mwave + mi * 16 + lr) * 64 + cbA);
#pragma unroll
      for (int h = 0; h < 2; h++)
#pragma unroll
        for (int ni = 0; ni < 2; ni++)
          bfr[h][ni] = *(const bf16x8*)(lB + (h * 64 + nwave + ni * 16 + lr) * 64 + cbA);
#pragma unroll
      for (int h = 0; h < 2; h++)
#pragma unroll
        for (int mi = 0; mi < 4; mi++)
#pragma unroll
          for (int ni = 0; ni < 2; ni++)
            acc[h][mi][ni] = __builtin_amdgcn_mfma_f32_16x16x32_bf16(af[mi], bfr[h][ni], acc[h][mi][ni], 0, 0, 0);
    }
    __syncthreads();
  }

#pragma unroll
  for (int mi = 0; mi < 4; mi++) {
    int row0 = mt * 128 + mwave + mi * 16 + lq * 4;
    float4 G[4];
#pragma unroll
    for (int r = 0; r < 4; r++) G[r] = ((const float4*)g4)[row0 + r];
#pragma unroll
    for (int ni = 0; ni < 2; ni++) {
      int col = ct * 64 + nwave + ni * 16 + lr;
      float b20 = b2[col], b21 = b2[768 + col];
#pragma unroll
      for (int r = 0; r < 4; r++) {
        float gw = (col < 96) ? G[r].x : (col < 192) ? G[r].y : (col < 384) ? G[r].z : G[r].w;
        float o = (acc[0][mi][ni][r] + b20) + (acc[1][mi][ni][r] + b21);
        size_t idx = (size_t)(row0 + r) * DIM + col;
        out[idx] = x[idx] + gw * o;
      }
    }
  }
}

extern "C" void kernel_launch(void* const* d_in, const int* in_sizes, int n_in,
                              void* d_out, int out_size, void* d_ws, size_t ws_size,
                              hipStream_t stream) {
  const float* x     = (const float*)d_in[0];
  const float* wr    = (const float*)d_in[1];
  const float* gamma = (const float*)d_in[2];
  const float* beta  = (const float*)d_in[3];
  const float* w1    = (const float*)d_in[4];
  const float* b1    = (const float*)d_in[5];
  const float* w2    = (const float*)d_in[6];
  const float* b2    = (const float*)d_in[7];
  float* out = (float*)d_out;

  char* ws = (char*)d_ws;
  float*  probs    = (float*)(ws + 0);            // 131072
  float*  gate_tok = (float*)(ws + 131072);       // 131072
  float*  cntf     = (float*)(ws + 262144);       // 32768
  float*  g4       = (float*)(ws + 294912);       // 131072
  bf16_t* w1b      = (bf16_t*)(ws + 425984);      // 8257536
  bf16_t* w2b      = (bf16_t*)(ws + 8683520);     // 11796480
  bf16_t* ytil     = (bf16_t*)(ws + 20480000);    // 12582912
  bf16_t* y2b      = (bf16_t*)(ws + 33062912);    // 62914560
  bf16_t* qb       = (bf16_t*)(ws + 95977472);    // 12582912
  bf16_t* kb       = (bf16_t*)(ws + 108560384);   // 12582912
  bf16_t* vtb      = (bf16_t*)(ws + 121143296);   // 12582912

  cast_router_kernel<<<4096, 256, 0, stream>>>(w1, w2, w1b, w2b, x, wr, probs);
  rank_kernel<<<dim3(4, 32), 256, 0, stream>>>(probs, gate_tok);
  ln_kernel<<<2048, 256, 0, stream>>>(x, gamma, beta, gate_tok, ytil, cntf, g4);
  fc1_kernel<<<2688, 256, 0, stream>>>(ytil, w1b, b1, cntf, y2b, qb, kb, vtb);
  attn_kernel<<<768, 256, 0, stream>>>(qb, kb, vtb, y2b);
  fc2_kernel<<<768, 256, 0, stream>>>(y2b, w2b, b2, g4, x, out);
}

// Round 7
// 378.002 us; speedup vs baseline: 1.0121x; 1.0121x over previous
//
#include <hip/hip_runtime.h>
#include <math.h>

typedef __bf16 bf16_t;
typedef __bf16 bf16x8 __attribute__((ext_vector_type(8)));
typedef __bf16 bf16x4 __attribute__((ext_vector_type(4)));
typedef float f32x4 __attribute__((ext_vector_type(4)));

#define DIM 768
#define NE 4
#define NH 12
#define HD 64
#define MLP_HID 3072
#define FC1_OUT 5376
#define FC2_IN 3840
#define CAP 512
#define LOG2E 1.44269504088896340736f

__device__ __forceinline__ void async_copy16(const void* g, void* l) {
  __builtin_amdgcn_global_load_lds((const __attribute__((address_space(1))) void*)g,
                                   (__attribute__((address_space(3))) void*)l, 16, 0, 0);
}

// sigmoid-form tanh-GELU: gelu(v) = v * rcp(1 + exp2(v*(c1 + c2*v^2)))
// max abs dev from exact-erf gelu ~7e-4 -- invisible at bf16.
__device__ __forceinline__ float gelu_f(float v) {
  float v2 = v * v;
  float t = v * fmaf(-0.102944f, v2, -2.302208f);
  float e = exp2f(t);
  return v * __builtin_amdgcn_rcpf(1.0f + e);
}

// ---------------- fused: weight cast (blocks 0..2047) + router softmax (blocks 2048..4095) ----------------
__global__ __launch_bounds__(256) void cast_router_kernel(const float* __restrict__ w1,
                                                          const float* __restrict__ w2,
                                                          bf16_t* __restrict__ w1b,
                                                          bf16_t* __restrict__ w2b,
                                                          const float* __restrict__ x,
                                                          const float* __restrict__ wr,
                                                          float* __restrict__ probs) {
  if (blockIdx.x < 2048) {
    const int N1 = FC1_OUT * DIM / 4;     // 1032192 float4s
    const int N2 = 1536 * FC2_IN / 4;     // 1474560 float4s
    const float4* w1v = (const float4*)w1;
    const float4* w2v = (const float4*)w2;
    for (int i = blockIdx.x * 256 + threadIdx.x; i < N1 + N2; i += 2048 * 256) {
      float4 f;
      bf16_t* dst;
      if (i < N1) { f = w1v[i]; dst = w1b + (size_t)i * 4; }
      else        { f = w2v[i - N1]; dst = w2b + (size_t)(i - N1) * 4; }
      bf16x4 o;
      o[0] = (bf16_t)f.x; o[1] = (bf16_t)f.y; o[2] = (bf16_t)f.z; o[3] = (bf16_t)f.w;
      *(bf16x4*)dst = o;
    }
    return;
  }
  int t = (blockIdx.x - 2048) * 4 + (threadIdx.x >> 6);
  int l = threadIdx.x & 63;
  const float4* xr = (const float4*)(x + (size_t)t * DIM);
  const float4* wr4 = (const float4*)wr;
  float a0 = 0.f, a1 = 0.f, a2 = 0.f, a3 = 0.f;
#pragma unroll
  for (int i = 0; i < 3; i++) {
    int d4 = l + i * 64;                  // float4 index within row (768/4 = 192)
    float4 xv = xr[d4];
    float4 w0 = wr4[d4];
    float4 w1e = wr4[192 + d4];
    float4 w2e = wr4[384 + d4];
    float4 w3e = wr4[576 + d4];
    a0 += xv.x * w0.x + xv.y * w0.y + xv.z * w0.z + xv.w * w0.w;
    a1 += xv.x * w1e.x + xv.y * w1e.y + xv.z * w1e.z + xv.w * w1e.w;
    a2 += xv.x * w2e.x + xv.y * w2e.y + xv.z * w2e.z + xv.w * w2e.w;
    a3 += xv.x * w3e.x + xv.y * w3e.y + xv.z * w3e.z + xv.w * w3e.w;
  }
#pragma unroll
  for (int off = 32; off > 0; off >>= 1) {
    a0 += __shfl_down(a0, off);
    a1 += __shfl_down(a1, off);
    a2 += __shfl_down(a2, off);
    a3 += __shfl_down(a3, off);
  }
  if (l == 0) {
    float m = fmaxf(fmaxf(a0, a1), fmaxf(a2, a3));
    float e0 = expf(a0 - m), e1 = expf(a1 - m), e2 = expf(a2 - m), e3 = expf(a3 - m);
    float inv = 1.0f / (e0 + e1 + e2 + e3);
    int b = t >> 10, n = t & 1023;
    probs[(b * NE + 0) * 1024 + n] = e0 * inv;
    probs[(b * NE + 1) * 1024 + n] = e1 * inv;
    probs[(b * NE + 2) * 1024 + n] = e2 * inv;
    probs[(b * NE + 3) * 1024 + n] = e3 * inv;
  }
}

// ---------------- exact top-k membership via ranking ----------------
__global__ __launch_bounds__(256) void rank_kernel(const float* __restrict__ probs,
                                                   float* __restrict__ gate_tok) {
  int be = blockIdx.y;
  __shared__ float p[1024];
  for (int i = threadIdx.x; i < 1024; i += 256) p[i] = probs[be * 1024 + i];
  __syncthreads();
  int n = blockIdx.x * 256 + threadIdx.x;
  float pn = p[n];
  int rank = 0;
  for (int j = 0; j < 1024; j++) {
    float pj = p[j];
    rank += (pj > pn) || (pj == pn && j < n);
  }
  int b = be >> 2, e = be & 3;
  gate_tok[(size_t)((b << 10) + n) * 4 + e] = (rank < CAP) ? pn : 0.0f;
}

// ---------------- LayerNorm + segment-count scaling -> bf16; emit gate suffix sums ----------------
__global__ __launch_bounds__(256) void ln_kernel(const float* __restrict__ x,
                                                 const float* __restrict__ gamma,
                                                 const float* __restrict__ beta,
                                                 const float* __restrict__ gate_tok,
                                                 bf16_t* __restrict__ ytil,
                                                 float* __restrict__ cntf,
                                                 float* __restrict__ g4) {
  int t = blockIdx.x * 4 + (threadIdx.x >> 6);
  int l = threadIdx.x & 63;
  float4 gg = ((const float4*)gate_tok)[t];
  float s0 = (gg.x > 0.f) ? 1.f : 0.f;
  float s1 = (gg.y > 0.f) ? 1.f : 0.f;
  float s2 = (gg.z > 0.f) ? 1.f : 0.f;
  float s3 = (gg.w > 0.f) ? 1.f : 0.f;
  float c3 = s3, c2 = c3 + s2, c1 = c2 + s1, c0 = c1 + s0;
  if (l == 0) {
    cntf[t] = c0;
    float4 G;
    G.x = gg.x + gg.y + gg.z + gg.w;
    G.y = gg.y + gg.z + gg.w;
    G.z = gg.z + gg.w;
    G.w = gg.w;
    ((float4*)g4)[t] = G;
  }
  const float4* xr = (const float4*)(x + (size_t)t * DIM);
  const float4* gm4 = (const float4*)gamma;
  const float4* bt4 = (const float4*)beta;
  float4 v[3];
  float s = 0.f, sq = 0.f;
#pragma unroll
  for (int i = 0; i < 3; i++) {
    v[i] = xr[l + i * 64];
    s += v[i].x + v[i].y + v[i].z + v[i].w;
    sq += v[i].x * v[i].x + v[i].y * v[i].y + v[i].z * v[i].z + v[i].w * v[i].w;
  }
#pragma unroll
  for (int off = 1; off < 64; off <<= 1) {
    s += __shfl_xor(s, off);
    sq += __shfl_xor(sq, off);
  }
  float mean = s * (1.0f / DIM);
  float var = sq * (1.0f / DIM) - mean * mean;
  float rs = rsqrtf(var + 1e-6f);
#pragma unroll
  for (int i = 0; i < 3; i++) {
    int d4 = l + i * 64;
    int d0 = d4 * 4;
    float cf = (d0 < 96) ? c0 : (d0 < 192) ? c1 : (d0 < 384) ? c2 : c3;
    float4 gmv = gm4[d4], btv = bt4[d4];
    bf16x4 o;
    o[0] = (bf16_t)(((v[i].x - mean) * rs * gmv.x + btv.x) * cf);
    o[1] = (bf16_t)(((v[i].y - mean) * rs * gmv.y + btv.y) * cf);
    o[2] = (bf16_t)(((v[i].z - mean) * rs * gmv.z + btv.z) * cf);
    o[3] = (bf16_t)(((v[i].w - mean) * rs * gmv.w + btv.w) * cf);
    *(bf16x4*)(ytil + (size_t)t * DIM + d0) = o;
  }
}

// ---------------- FC1 dense: [8192,5376] = ytil @ w1^T + cnt*b1; epilogue gelu / qkv split ----------------
// Q is pre-scaled by 0.125*log2e so attention scores are directly in log2 units.
// vtb (transposed V): token axis permuted within each 64-block by kappa^-1 (tau=32a+16c+4b+d stored
// at column 32a+8b+4c+d) so attn's swapped-QK P-fragments align with V octets with ZERO shuffles.
__global__ __launch_bounds__(256, 4) void fc1_kernel(const bf16_t* __restrict__ ytil,
                                                     const bf16_t* __restrict__ w1b,
                                                     const float* __restrict__ b1,
                                                     const float* __restrict__ cntf,
                                                     bf16_t* __restrict__ y2b,
                                                     bf16_t* __restrict__ qb,
                                                     bf16_t* __restrict__ kb,
                                                     bf16_t* __restrict__ vtb) {
  const int bid = blockIdx.x;
  const int xcd = bid & 7, j = bid >> 3;      // j in 0..335
  const int mt = xcd * 8 + (j & 7);           // 0..63 (fast within XCD)
  const int nt = j >> 3;                      // 0..41 (slow)
  const int tid = threadIdx.x;
  const int w = tid >> 6, l = tid & 63;
  const int lq = l >> 4, lr = l & 15;

  __shared__ __align__(16) bf16_t lA[128 * 64];
  __shared__ __align__(16) bf16_t lB[128 * 64];

  f32x4 acc[4][4] = {};
  const int mwave = (w & 1) * 64, nwave = (w >> 1) * 64;
  const int crow = l >> 3;
  const int cbg = (l & 7) ^ (crow & 7);

  for (int k0 = 0; k0 < DIM; k0 += 64) {
#pragma unroll
    for (int i = 0; i < 4; i++) {
      int c = w * 4 + i;
      int row = c * 8 + crow;
      async_copy16(ytil + (size_t)(mt * 128 + row) * DIM + k0 + cbg * 8, lA + c * 512);
      async_copy16(w1b + (size_t)(nt * 128 + row) * DIM + k0 + cbg * 8, lB + c * 512);
    }
    __syncthreads();
#pragma unroll
    for (int ks = 0; ks < 2; ks++) {
      const int cbA = ((ks * 4 + lq) ^ (lr & 7)) * 8;
      bf16x8 af[4], bfr[4];
#pragma unroll
      for (int mi = 0; mi < 4; mi++)
        af[mi] = *(const bf16x8*)(lA + (mwave + mi * 16 + lr) * 64 + cbA);
#pragma unroll
      for (int ni = 0; ni < 4; ni++)
        bfr[ni] = *(const bf16x8*)(lB + (nwave + ni * 16 + lr) * 64 + cbA);
#pragma unroll
      for (int mi = 0; mi < 4; mi++)
#pragma unroll
        for (int ni = 0; ni < 4; ni++)
          acc[mi][ni] = __builtin_amdgcn_mfma_f32_16x16x32_bf16(af[mi], bfr[ni], acc[mi][ni], 0, 0, 0);
    }
    __syncthreads();
  }

#pragma unroll
  for (int mi = 0; mi < 4; mi++) {
    int row0 = mt * 128 + mwave + mi * 16 + lq * 4;
    float cnt[4];
#pragma unroll
    for (int r = 0; r < 4; r++) cnt[r] = cntf[row0 + r];
#pragma unroll
    for (int ni = 0; ni < 4; ni++) {
      int col = nt * 128 + nwave + ni * 16 + lr;
      float bias = b1[col];
      if (col < MLP_HID) {
#pragma unroll
        for (int r = 0; r < 4; r++) {
          float v = acc[mi][ni][r] + cnt[r] * bias;
          y2b[(size_t)(row0 + r) * FC2_IN + col] = (bf16_t)gelu_f(v);
        }
      } else {
        int part = col - MLP_HID;
        int comp = (part >= 1536) ? 2 : (part >= 768) ? 1 : 0;
        int rem = part - comp * 768;
        int hh = rem >> 6, d = rem & 63;
        int b = row0 >> 10, n0 = row0 & 1023;
        size_t base = (size_t)(b * NH + hh);
        if (comp == 2) {
          bf16x4 pk;
#pragma unroll
          for (int r = 0; r < 4; r++)
            pk[r] = (bf16_t)(acc[mi][ni][r] + cnt[r] * bias);
          // kappa^-1 permutation of token-offset within the 64-block (8B-quad granular):
          // off = 32a+16th+4tm (tl=0)  ->  32a+8tm+4th
          int n0p = (n0 & ~63) | (n0 & 32) | (((n0 >> 2) & 3) << 3) | (((n0 >> 4) & 1) << 2);
          *(bf16x4*)(vtb + (base * HD + d) * 1024 + n0p) = pk;
        } else {
#pragma unroll
          for (int r = 0; r < 4; r++) {
            float v = acc[mi][ni][r] + cnt[r] * bias;
            if (comp == 0) qb[(base * 1024 + n0 + r) * HD + d] = (bf16_t)(v * (0.125f * LOG2E));
            else           kb[(base * 1024 + n0 + r) * HD + d] = (bf16_t)v;
          }
        }
      }
    }
  }
}

// ---------------- flash attention, swapped QK^T, fully in-register softmax ----------------
// kf/vf fragments are IDENTICAL for both q-halves h -- read each ONCE per kt and feed both
// halves' MFMAs (h innermost): LDS b128 reads per kt per wave 32 -> 16. sacc/pf for both h
// are live simultaneously (+~32 VGPR, all indices compile-time).
__global__ __launch_bounds__(256) void attn_kernel(const bf16_t* __restrict__ qb,
                                                   const bf16_t* __restrict__ kb,
                                                   const bf16_t* __restrict__ vtb,
                                                   bf16_t* __restrict__ y2b) {
  const int bid = blockIdx.x;                 // 0..767
  const int xcd = bid & 7, j = bid >> 3;      // j 0..95
  const int bh = xcd * 12 + (j >> 3);         // all 8 q-blocks of a head on one XCD
  const int qt = j & 7;                       // 128-row q tile
  const int tid = threadIdx.x;
  const int w = tid >> 6, l = tid & 63, lq = l >> 4, lr = l & 15;

  __shared__ __align__(16) bf16_t lK[2][64 * 64];
  __shared__ __align__(16) bf16_t lV[2][64 * 64];

  const bf16_t* qbase = qb + (size_t)bh * 1024 * HD;
  const bf16_t* kbase = kb + (size_t)bh * 1024 * HD;
  const bf16_t* vbase = vtb + (size_t)bh * HD * 1024;

  bf16x8 qf[2][2];
#pragma unroll
  for (int h = 0; h < 2; h++) {
    int qrow = qt * 128 + h * 64 + w * 16 + lr;
#pragma unroll
    for (int s = 0; s < 2; s++)
      qf[h][s] = *(const bf16x8*)(qbase + (size_t)qrow * HD + s * 32 + lq * 8);
  }

  f32x4 oacc[2][4] = {};
  float psum[2] = {0.f, 0.f};

  const int crow = l >> 3;
  const int cbg = (l & 7) ^ (crow & 7);

  auto stage = [&](int buf, int kt) {
#pragma unroll
    for (int i = 0; i < 2; i++) {
      int c = w * 2 + i;
      int row = c * 8 + crow;
      async_copy16(kbase + (size_t)(kt * 64 + row) * HD + cbg * 8, &lK[buf][c * 512]);
      async_copy16(vbase + (size_t)row * 1024 + kt * 64 + cbg * 8, &lV[buf][c * 512]);
    }
  };

  stage(0, 0);
  __syncthreads();

  int cur = 0;
  for (int kt = 0; kt < 16; kt++) {
    if (kt + 1 < 16) stage(cur ^ 1, kt + 1);

    // QK^T for both halves; each kf read once
    f32x4 sacc[2][4] = {};
#pragma unroll
    for (int s = 0; s < 2; s++) {
      const int cb = ((s * 4 + lq) ^ (lr & 7)) * 8;
#pragma unroll
      for (int kbq = 0; kbq < 4; kbq++) {
        bf16x8 kf = *(const bf16x8*)(&lK[cur][(kbq * 16 + lr) * 64 + cb]);
#pragma unroll
        for (int h = 0; h < 2; h++)
          sacc[h][kbq] = __builtin_amdgcn_mfma_f32_16x16x32_bf16(kf, qf[h][s], sacc[h][kbq], 0, 0, 0);
      }
    }

    // in-register softmax: S^T lane layout = 16 tokens (16kbq+4lq+r) of ONE q-row (qb0+lr)
    bf16x8 pf[2][2];
#pragma unroll
    for (int h = 0; h < 2; h++) {
      float p[4][4];
#pragma unroll
      for (int kbq = 0; kbq < 4; kbq++)
#pragma unroll
        for (int r = 0; r < 4; r++) {
          p[kbq][r] = exp2f(sacc[h][kbq][r]);
          psum[h] += p[kbq][r];
        }
#pragma unroll
      for (int ks = 0; ks < 2; ks++)
#pragma unroll
        for (int jj = 0; jj < 8; jj++)
          pf[h][ks][jj] = (bf16_t)p[2 * ks + (jj >> 2)][jj & 3];
    }

    // PV for both halves; each vf read once
#pragma unroll
    for (int ks = 0; ks < 2; ks++) {
      const int cb = ((ks * 4 + lq) ^ (lr & 7)) * 8;
#pragma unroll
      for (int nb = 0; nb < 4; nb++) {
        bf16x8 vf = *(const bf16x8*)(&lV[cur][(nb * 16 + lr) * 64 + cb]);
#pragma unroll
        for (int h = 0; h < 2; h++)
          oacc[h][nb] = __builtin_amdgcn_mfma_f32_16x16x32_bf16(pf[h][ks], vf, oacc[h][nb], 0, 0, 0);
      }
    }

    __syncthreads();
    cur ^= 1;
  }

  int b = bh / NH, hh = bh % NH;
#pragma unroll
  for (int h = 0; h < 2; h++) {
    float ps = psum[h];
    ps += __shfl_xor(ps, 16);
    ps += __shfl_xor(ps, 32);     // full row-sum for q-row (w*16 + lr), uniform across lq
    float rinv[4];
#pragma unroll
    for (int r = 0; r < 4; r++) rinv[r] = 1.0f / __shfl(ps, lq * 4 + r);  // C rows = lq*4+r
#pragma unroll
    for (int nb = 0; nb < 4; nb++)
#pragma unroll
      for (int r = 0; r < 4; r++) {
        float v = oacc[h][nb][r] * rinv[r];
        int tok = qt * 128 + h * 64 + w * 16 + lq * 4 + r;
        y2b[((size_t)(b * 1024 + tok)) * FC2_IN + MLP_HID + hh * HD + nb * 16 + lr] = (bf16_t)v;
      }
  }
}

// ---------------- FC2 dense fused: out = x + Sum_halves G_seg(col) * (y2 @ w2^T + b2) ----------------
// Round-0 proven structure: 128x128 tile, 256 thr, single-buffered LDS, 3 blocks/CU implicit overlap.
__global__ __launch_bounds__(256, 4) void fc2_kernel(const bf16_t* __restrict__ y2b,
                                                     const bf16_t* __restrict__ w2b,
                                                     const float* __restrict__ b2,
                                                     const float* __restrict__ g4,
                                                     const float* __restrict__ x,
                                                     float* __restrict__ out) {
  const int bid = blockIdx.x;
  const int xcd = bid & 7, j = bid >> 3;
  const int mt = xcd * 8 + j / 12;
  const int ct = j % 12;
  const int tid = threadIdx.x;
  const int w = tid >> 6, l = tid & 63;
  const int lq = l >> 4, lr = l & 15;

  __shared__ __align__(16) bf16_t lA[128 * 64];
  __shared__ __align__(16) bf16_t lB[128 * 64];

  f32x4 acc[2][4][2] = {};
  const int mwave = (w & 1) * 64, nwave = (w >> 1) * 32;
  const int crow = l >> 3;
  const int cbg = (l & 7) ^ (crow & 7);

  for (int k0 = 0; k0 < FC2_IN; k0 += 64) {
#pragma unroll
    for (int i = 0; i < 4; i++) {
      int c = w * 4 + i;
      int row = c * 8 + crow;
      async_copy16(y2b + (size_t)(mt * 128 + row) * FC2_IN + k0 + cbg * 8, lA + c * 512);
      int grow = ((row >> 6) * 768) + ct * 64 + (row & 63);
      async_copy16(w2b + (size_t)grow * FC2_IN + k0 + cbg * 8, lB + c * 512);
    }
    __syncthreads();
#pragma unroll
    for (int ks = 0; ks < 2; ks++) {
      const int cbA = ((ks * 4 + lq) ^ (lr & 7)) * 8;
      bf16x8 af[4], bfr[2][2];
#pragma unroll
      for (int mi = 0; mi < 4; mi++)
        af[mi] = *(const bf16x8*)(lA + (mwave + mi * 16 + lr) * 64 + cbA);
#pragma unroll
      for (int h = 0; h < 2; h++)
#pragma unroll
        for (int ni = 0; ni < 2; ni++)
          bfr[h][ni] = *(const bf16x8*)(lB + (h * 64 + nwave + ni * 16 + lr) * 64 + cbA);
#pragma unroll
      for (int h = 0; h < 2; h++)
#pragma unroll
        for (int mi = 0; mi < 4; mi++)
#pragma unroll
          for (int ni = 0; ni < 2; ni++)
            acc[h][mi][ni] = __builtin_amdgcn_mfma_f32_16x16x32_bf16(af[mi], bfr[h][ni], acc[h][mi][ni], 0, 0, 0);
    }
    __syncthreads();
  }

#pragma unroll
  for (int mi = 0; mi < 4; mi++) {
    int row0 = mt * 128 + mwave + mi * 16 + lq * 4;
    float4 G[4];
#pragma unroll
    for (int r = 0; r < 4; r++) G[r] = ((const float4*)g4)[row0 + r];
#pragma unroll
    for (int ni = 0; ni < 2; ni++) {
      int col = ct * 64 + nwave + ni * 16 + lr;
      float b20 = b2[col], b21 = b2[768 + col];
#pragma unroll
      for (int r = 0; r < 4; r++) {
        float gw = (col < 96) ? G[r].x : (col < 192) ? G[r].y : (col < 384) ? G[r].z : G[r].w;
        float o = (acc[0][mi][ni][r] + b20) + (acc[1][mi][ni][r] + b21);
        size_t idx = (size_t)(row0 + r) * DIM + col;
        out[idx] = x[idx] + gw * o;
      }
    }
  }
}

extern "C" void kernel_launch(void* const* d_in, const int* in_sizes, int n_in,
                              void* d_out, int out_size, void* d_ws, size_t ws_size,
                              hipStream_t stream) {
  const float* x     = (const float*)d_in[0];
  const float* wr    = (const float*)d_in[1];
  const float* gamma = (const float*)d_in[2];
  const float* beta  = (const float*)d_in[3];
  const float* w1    = (const float*)d_in[4];
  const float* b1    = (const float*)d_in[5];
  const float* w2    = (const float*)d_in[6];
  const float* b2    = (const float*)d_in[7];
  float* out = (float*)d_out;

  char* ws = (char*)d_ws;
  float*  probs    = (float*)(ws + 0);            // 131072
  float*  gate_tok = (float*)(ws + 131072);       // 131072
  float*  cntf     = (float*)(ws + 262144);       // 32768
  float*  g4       = (float*)(ws + 294912);       // 131072
  bf16_t* w1b      = (bf16_t*)(ws + 425984);      // 8257536
  bf16_t* w2b      = (bf16_t*)(ws + 8683520);     // 11796480
  bf16_t* ytil     = (bf16_t*)(ws + 20480000);    // 12582912
  bf16_t* y2b      = (bf16_t*)(ws + 33062912);    // 62914560
  bf16_t* qb       = (bf16_t*)(ws + 95977472);    // 12582912
  bf16_t* kb       = (bf16_t*)(ws + 108560384);   // 12582912
  bf16_t* vtb      = (bf16_t*)(ws + 121143296);   // 12582912

  cast_router_kernel<<<4096, 256, 0, stream>>>(w1, w2, w1b, w2b, x, wr, probs);
  rank_kernel<<<dim3(4, 32), 256, 0, stream>>>(probs, gate_tok);
  ln_kernel<<<2048, 256, 0, stream>>>(x, gamma, beta, gate_tok, ytil, cntf, g4);
  fc1_kernel<<<2688, 256, 0, stream>>>(ytil, w1b, b1, cntf, y2b, qb, kb, vtb);
  attn_kernel<<<768, 256, 0, stream>>>(qb, kb, vtb, y2b);
  fc2_kernel<<<768, 256, 0, stream>>>(y2b, w2b, b2, g4, x, out);
}

// Round 8
// 364.310 us; speedup vs baseline: 1.0501x; 1.0376x over previous
//
#include <hip/hip_runtime.h>
#include <math.h>

typedef __bf16 bf16_t;
typedef __bf16 bf16x8 __attribute__((ext_vector_type(8)));
typedef __bf16 bf16x4 __attribute__((ext_vector_type(4)));
typedef float f32x4 __attribute__((ext_vector_type(4)));

#define DIM 768
#define NE 4
#define NH 12
#define HD 64
#define MLP_HID 3072
#define FC1_OUT 5376
#define FC2_IN 3840
#define CAP 512
#define LOG2E 1.44269504088896340736f

__device__ __forceinline__ void async_copy16(const void* g, void* l) {
  __builtin_amdgcn_global_load_lds((const __attribute__((address_space(1))) void*)g,
                                   (__attribute__((address_space(3))) void*)l, 16, 0, 0);
}

// sigmoid-form tanh-GELU: gelu(v) = v * rcp(1 + exp2(v*(c1 + c2*v^2)))
// max abs dev from exact-erf gelu ~7e-4 -- invisible at bf16.
__device__ __forceinline__ float gelu_f(float v) {
  float v2 = v * v;
  float t = v * fmaf(-0.102944f, v2, -2.302208f);
  float e = exp2f(t);
  return v * __builtin_amdgcn_rcpf(1.0f + e);
}

// ---------------- fused: weight cast (blocks 0..2047) + router softmax (blocks 2048..4095) ----------------
__global__ __launch_bounds__(256) void cast_router_kernel(const float* __restrict__ w1,
                                                          const float* __restrict__ w2,
                                                          bf16_t* __restrict__ w1b,
                                                          bf16_t* __restrict__ w2b,
                                                          const float* __restrict__ x,
                                                          const float* __restrict__ wr,
                                                          float* __restrict__ probs) {
  if (blockIdx.x < 2048) {
    const int N1 = FC1_OUT * DIM / 4;     // 1032192 float4s
    const int N2 = 1536 * FC2_IN / 4;     // 1474560 float4s
    const float4* w1v = (const float4*)w1;
    const float4* w2v = (const float4*)w2;
    for (int i = blockIdx.x * 256 + threadIdx.x; i < N1 + N2; i += 2048 * 256) {
      float4 f;
      bf16_t* dst;
      if (i < N1) { f = w1v[i]; dst = w1b + (size_t)i * 4; }
      else        { f = w2v[i - N1]; dst = w2b + (size_t)(i - N1) * 4; }
      bf16x4 o;
      o[0] = (bf16_t)f.x; o[1] = (bf16_t)f.y; o[2] = (bf16_t)f.z; o[3] = (bf16_t)f.w;
      *(bf16x4*)dst = o;
    }
    return;
  }
  int t = (blockIdx.x - 2048) * 4 + (threadIdx.x >> 6);
  int l = threadIdx.x & 63;
  const float4* xr = (const float4*)(x + (size_t)t * DIM);
  const float4* wr4 = (const float4*)wr;
  float a0 = 0.f, a1 = 0.f, a2 = 0.f, a3 = 0.f;
#pragma unroll
  for (int i = 0; i < 3; i++) {
    int d4 = l + i * 64;                  // float4 index within row (768/4 = 192)
    float4 xv = xr[d4];
    float4 w0 = wr4[d4];
    float4 w1e = wr4[192 + d4];
    float4 w2e = wr4[384 + d4];
    float4 w3e = wr4[576 + d4];
    a0 += xv.x * w0.x + xv.y * w0.y + xv.z * w0.z + xv.w * w0.w;
    a1 += xv.x * w1e.x + xv.y * w1e.y + xv.z * w1e.z + xv.w * w1e.w;
    a2 += xv.x * w2e.x + xv.y * w2e.y + xv.z * w2e.z + xv.w * w2e.w;
    a3 += xv.x * w3e.x + xv.y * w3e.y + xv.z * w3e.z + xv.w * w3e.w;
  }
#pragma unroll
  for (int off = 32; off > 0; off >>= 1) {
    a0 += __shfl_down(a0, off);
    a1 += __shfl_down(a1, off);
    a2 += __shfl_down(a2, off);
    a3 += __shfl_down(a3, off);
  }
  if (l == 0) {
    float m = fmaxf(fmaxf(a0, a1), fmaxf(a2, a3));
    float e0 = expf(a0 - m), e1 = expf(a1 - m), e2 = expf(a2 - m), e3 = expf(a3 - m);
    float inv = 1.0f / (e0 + e1 + e2 + e3);
    int b = t >> 10, n = t & 1023;
    probs[(b * NE + 0) * 1024 + n] = e0 * inv;
    probs[(b * NE + 1) * 1024 + n] = e1 * inv;
    probs[(b * NE + 2) * 1024 + n] = e2 * inv;
    probs[(b * NE + 3) * 1024 + n] = e3 * inv;
  }
}

// ---------------- exact top-k membership via ranking ----------------
__global__ __launch_bounds__(256) void rank_kernel(const float* __restrict__ probs,
                                                   float* __restrict__ gate_tok) {
  int be = blockIdx.y;
  __shared__ float p[1024];
  for (int i = threadIdx.x; i < 1024; i += 256) p[i] = probs[be * 1024 + i];
  __syncthreads();
  int n = blockIdx.x * 256 + threadIdx.x;
  float pn = p[n];
  int rank = 0;
  for (int j = 0; j < 1024; j++) {
    float pj = p[j];
    rank += (pj > pn) || (pj == pn && j < n);
  }
  int b = be >> 2, e = be & 3;
  gate_tok[(size_t)((b << 10) + n) * 4 + e] = (rank < CAP) ? pn : 0.0f;
}

// ---------------- LayerNorm + segment-count scaling -> bf16; emit gate suffix sums ----------------
__global__ __launch_bounds__(256) void ln_kernel(const float* __restrict__ x,
                                                 const float* __restrict__ gamma,
                                                 const float* __restrict__ beta,
                                                 const float* __restrict__ gate_tok,
                                                 bf16_t* __restrict__ ytil,
                                                 float* __restrict__ cntf,
                                                 float* __restrict__ g4) {
  int t = blockIdx.x * 4 + (threadIdx.x >> 6);
  int l = threadIdx.x & 63;
  float4 gg = ((const float4*)gate_tok)[t];
  float s0 = (gg.x > 0.f) ? 1.f : 0.f;
  float s1 = (gg.y > 0.f) ? 1.f : 0.f;
  float s2 = (gg.z > 0.f) ? 1.f : 0.f;
  float s3 = (gg.w > 0.f) ? 1.f : 0.f;
  float c3 = s3, c2 = c3 + s2, c1 = c2 + s1, c0 = c1 + s0;
  if (l == 0) {
    cntf[t] = c0;
    float4 G;
    G.x = gg.x + gg.y + gg.z + gg.w;
    G.y = gg.y + gg.z + gg.w;
    G.z = gg.z + gg.w;
    G.w = gg.w;
    ((float4*)g4)[t] = G;
  }
  const float4* xr = (const float4*)(x + (size_t)t * DIM);
  const float4* gm4 = (const float4*)gamma;
  const float4* bt4 = (const float4*)beta;
  float4 v[3];
  float s = 0.f, sq = 0.f;
#pragma unroll
  for (int i = 0; i < 3; i++) {
    v[i] = xr[l + i * 64];
    s += v[i].x + v[i].y + v[i].z + v[i].w;
    sq += v[i].x * v[i].x + v[i].y * v[i].y + v[i].z * v[i].z + v[i].w * v[i].w;
  }
#pragma unroll
  for (int off = 1; off < 64; off <<= 1) {
    s += __shfl_xor(s, off);
    sq += __shfl_xor(sq, off);
  }
  float mean = s * (1.0f / DIM);
  float var = sq * (1.0f / DIM) - mean * mean;
  float rs = rsqrtf(var + 1e-6f);
#pragma unroll
  for (int i = 0; i < 3; i++) {
    int d4 = l + i * 64;
    int d0 = d4 * 4;
    float cf = (d0 < 96) ? c0 : (d0 < 192) ? c1 : (d0 < 384) ? c2 : c3;
    float4 gmv = gm4[d4], btv = bt4[d4];
    bf16x4 o;
    o[0] = (bf16_t)(((v[i].x - mean) * rs * gmv.x + btv.x) * cf);
    o[1] = (bf16_t)(((v[i].y - mean) * rs * gmv.y + btv.y) * cf);
    o[2] = (bf16_t)(((v[i].z - mean) * rs * gmv.z + btv.z) * cf);
    o[3] = (bf16_t)(((v[i].w - mean) * rs * gmv.w + btv.w) * cf);
    *(bf16x4*)(ytil + (size_t)t * DIM + d0) = o;
  }
}

// ---------------- FC1 dense: [8192,5376] = ytil @ w1^T + cnt*b1; epilogue gelu / qkv split ----------------
// Q is pre-scaled by 0.125*log2e so attention scores are directly in log2 units.
// vtb (transposed V): token axis permuted within each 64-block by kappa^-1 (tau=32a+16c+4b+d stored
// at column 32a+8b+4c+d) so attn's swapped-QK P-fragments align with V octets with ZERO shuffles.
__global__ __launch_bounds__(256, 4) void fc1_kernel(const bf16_t* __restrict__ ytil,
                                                     const bf16_t* __restrict__ w1b,
                                                     const float* __restrict__ b1,
                                                     const float* __restrict__ cntf,
                                                     bf16_t* __restrict__ y2b,
                                                     bf16_t* __restrict__ qb,
                                                     bf16_t* __restrict__ kb,
                                                     bf16_t* __restrict__ vtb) {
  const int bid = blockIdx.x;
  const int xcd = bid & 7, j = bid >> 3;      // j in 0..335
  const int mt = xcd * 8 + (j & 7);           // 0..63 (fast within XCD)
  const int nt = j >> 3;                      // 0..41 (slow)
  const int tid = threadIdx.x;
  const int w = tid >> 6, l = tid & 63;
  const int lq = l >> 4, lr = l & 15;

  __shared__ __align__(16) bf16_t lA[128 * 64];
  __shared__ __align__(16) bf16_t lB[128 * 64];

  f32x4 acc[4][4] = {};
  const int mwave = (w & 1) * 64, nwave = (w >> 1) * 64;
  const int crow = l >> 3;
  const int cbg = (l & 7) ^ (crow & 7);

  for (int k0 = 0; k0 < DIM; k0 += 64) {
#pragma unroll
    for (int i = 0; i < 4; i++) {
      int c = w * 4 + i;
      int row = c * 8 + crow;
      async_copy16(ytil + (size_t)(mt * 128 + row) * DIM + k0 + cbg * 8, lA + c * 512);
      async_copy16(w1b + (size_t)(nt * 128 + row) * DIM + k0 + cbg * 8, lB + c * 512);
    }
    __syncthreads();
#pragma unroll
    for (int ks = 0; ks < 2; ks++) {
      const int cbA = ((ks * 4 + lq) ^ (lr & 7)) * 8;
      bf16x8 af[4], bfr[4];
#pragma unroll
      for (int mi = 0; mi < 4; mi++)
        af[mi] = *(const bf16x8*)(lA + (mwave + mi * 16 + lr) * 64 + cbA);
#pragma unroll
      for (int ni = 0; ni < 4; ni++)
        bfr[ni] = *(const bf16x8*)(lB + (nwave + ni * 16 + lr) * 64 + cbA);
#pragma unroll
      for (int mi = 0; mi < 4; mi++)
#pragma unroll
        for (int ni = 0; ni < 4; ni++)
          acc[mi][ni] = __builtin_amdgcn_mfma_f32_16x16x32_bf16(af[mi], bfr[ni], acc[mi][ni], 0, 0, 0);
    }
    __syncthreads();
  }

#pragma unroll
  for (int mi = 0; mi < 4; mi++) {
    int row0 = mt * 128 + mwave + mi * 16 + lq * 4;
    float cnt[4];
#pragma unroll
    for (int r = 0; r < 4; r++) cnt[r] = cntf[row0 + r];
#pragma unroll
    for (int ni = 0; ni < 4; ni++) {
      int col = nt * 128 + nwave + ni * 16 + lr;
      float bias = b1[col];
      if (col < MLP_HID) {
#pragma unroll
        for (int r = 0; r < 4; r++) {
          float v = acc[mi][ni][r] + cnt[r] * bias;
          y2b[(size_t)(row0 + r) * FC2_IN + col] = (bf16_t)gelu_f(v);
        }
      } else {
        int part = col - MLP_HID;
        int comp = (part >= 1536) ? 2 : (part >= 768) ? 1 : 0;
        int rem = part - comp * 768;
        int hh = rem >> 6, d = rem & 63;
        int b = row0 >> 10, n0 = row0 & 1023;
        size_t base = (size_t)(b * NH + hh);
        if (comp == 2) {
          bf16x4 pk;
#pragma unroll
          for (int r = 0; r < 4; r++)
            pk[r] = (bf16_t)(acc[mi][ni][r] + cnt[r] * bias);
          // kappa^-1 permutation of token-offset within the 64-block (8B-quad granular):
          // off = 32a+16th+4tm (tl=0)  ->  32a+8tm+4th
          int n0p = (n0 & ~63) | (n0 & 32) | (((n0 >> 2) & 3) << 3) | (((n0 >> 4) & 1) << 2);
          *(bf16x4*)(vtb + (base * HD + d) * 1024 + n0p) = pk;
        } else {
#pragma unroll
          for (int r = 0; r < 4; r++) {
            float v = acc[mi][ni][r] + cnt[r] * bias;
            if (comp == 0) qb[(base * 1024 + n0 + r) * HD + d] = (bf16_t)(v * (0.125f * LOG2E));
            else           kb[(base * 1024 + n0 + r) * HD + d] = (bf16_t)v;
          }
        }
      }
    }
  }
}

// ---------------- flash attention, swapped QK^T, fully in-register softmax ----------------
// kf/vf read once per kt (h innermost). psum kept as 4 independent accumulators per half
// (8 chains: avoids the 16-deep serial add chain). setprio(1) around MFMA clusters (T5,
// attn regime: independent waves across blocks on the CU).
__global__ __launch_bounds__(256) void attn_kernel(const bf16_t* __restrict__ qb,
                                                   const bf16_t* __restrict__ kb,
                                                   const bf16_t* __restrict__ vtb,
                                                   bf16_t* __restrict__ y2b) {
  const int bid = blockIdx.x;                 // 0..767
  const int xcd = bid & 7, j = bid >> 3;      // j 0..95
  const int bh = xcd * 12 + (j >> 3);         // all 8 q-blocks of a head on one XCD
  const int qt = j & 7;                       // 128-row q tile
  const int tid = threadIdx.x;
  const int w = tid >> 6, l = tid & 63, lq = l >> 4, lr = l & 15;

  __shared__ __align__(16) bf16_t lK[2][64 * 64];
  __shared__ __align__(16) bf16_t lV[2][64 * 64];

  const bf16_t* qbase = qb + (size_t)bh * 1024 * HD;
  const bf16_t* kbase = kb + (size_t)bh * 1024 * HD;
  const bf16_t* vbase = vtb + (size_t)bh * HD * 1024;

  bf16x8 qf[2][2];
#pragma unroll
  for (int h = 0; h < 2; h++) {
    int qrow = qt * 128 + h * 64 + w * 16 + lr;
#pragma unroll
    for (int s = 0; s < 2; s++)
      qf[h][s] = *(const bf16x8*)(qbase + (size_t)qrow * HD + s * 32 + lq * 8);
  }

  f32x4 oacc[2][4] = {};
  float psum4[2][4] = {};

  const int crow = l >> 3;
  const int cbg = (l & 7) ^ (crow & 7);

  auto stage = [&](int buf, int kt) {
#pragma unroll
    for (int i = 0; i < 2; i++) {
      int c = w * 2 + i;
      int row = c * 8 + crow;
      async_copy16(kbase + (size_t)(kt * 64 + row) * HD + cbg * 8, &lK[buf][c * 512]);
      async_copy16(vbase + (size_t)row * 1024 + kt * 64 + cbg * 8, &lV[buf][c * 512]);
    }
  };

  stage(0, 0);
  __syncthreads();

  int cur = 0;
  for (int kt = 0; kt < 16; kt++) {
    if (kt + 1 < 16) stage(cur ^ 1, kt + 1);

    // QK^T for both halves; each kf read once
    f32x4 sacc[2][4] = {};
    __builtin_amdgcn_s_setprio(1);
#pragma unroll
    for (int s = 0; s < 2; s++) {
      const int cb = ((s * 4 + lq) ^ (lr & 7)) * 8;
#pragma unroll
      for (int kbq = 0; kbq < 4; kbq++) {
        bf16x8 kf = *(const bf16x8*)(&lK[cur][(kbq * 16 + lr) * 64 + cb]);
#pragma unroll
        for (int h = 0; h < 2; h++)
          sacc[h][kbq] = __builtin_amdgcn_mfma_f32_16x16x32_bf16(kf, qf[h][s], sacc[h][kbq], 0, 0, 0);
      }
    }
    __builtin_amdgcn_s_setprio(0);

    // in-register softmax: S^T lane layout = 16 tokens (16kbq+4lq+r) of ONE q-row (qb0+lr)
    bf16x8 pf[2][2];
#pragma unroll
    for (int h = 0; h < 2; h++) {
      float p[4][4];
#pragma unroll
      for (int kbq = 0; kbq < 4; kbq++)
#pragma unroll
        for (int r = 0; r < 4; r++) {
          p[kbq][r] = exp2f(sacc[h][kbq][r]);
          psum4[h][r] += p[kbq][r];      // 4 independent chains per half
        }
#pragma unroll
      for (int ks = 0; ks < 2; ks++)
#pragma unroll
        for (int jj = 0; jj < 8; jj++)
          pf[h][ks][jj] = (bf16_t)p[2 * ks + (jj >> 2)][jj & 3];
    }

    // PV for both halves; each vf read once
    __builtin_amdgcn_s_setprio(1);
#pragma unroll
    for (int ks = 0; ks < 2; ks++) {
      const int cb = ((ks * 4 + lq) ^ (lr & 7)) * 8;
#pragma unroll
      for (int nb = 0; nb < 4; nb++) {
        bf16x8 vf = *(const bf16x8*)(&lV[cur][(nb * 16 + lr) * 64 + cb]);
#pragma unroll
        for (int h = 0; h < 2; h++)
          oacc[h][nb] = __builtin_amdgcn_mfma_f32_16x16x32_bf16(pf[h][ks], vf, oacc[h][nb], 0, 0, 0);
      }
    }
    __builtin_amdgcn_s_setprio(0);

    __syncthreads();
    cur ^= 1;
  }

  int b = bh / NH, hh = bh % NH;
#pragma unroll
  for (int h = 0; h < 2; h++) {
    float ps = (psum4[h][0] + psum4[h][1]) + (psum4[h][2] + psum4[h][3]);
    ps += __shfl_xor(ps, 16);
    ps += __shfl_xor(ps, 32);     // full row-sum for q-row (w*16 + lr), uniform across lq
    float rinv[4];
#pragma unroll
    for (int r = 0; r < 4; r++) rinv[r] = 1.0f / __shfl(ps, lq * 4 + r);  // C rows = lq*4+r
#pragma unroll
    for (int nb = 0; nb < 4; nb++)
#pragma unroll
      for (int r = 0; r < 4; r++) {
        float v = oacc[h][nb][r] * rinv[r];
        int tok = qt * 128 + h * 64 + w * 16 + lq * 4 + r;
        y2b[((size_t)(b * 1024 + tok)) * FC2_IN + MLP_HID + hh * HD + nb * 16 + lr] = (bf16_t)v;
      }
  }
}

// ---------------- FC2 dense fused: out = x + Sum_halves G_seg(col) * (y2 @ w2^T + b2) ----------------
// Round-0 proven structure: 128x128 tile, 256 thr, single-buffered LDS, 3 blocks/CU implicit overlap.
__global__ __launch_bounds__(256, 4) void fc2_kernel(const bf16_t* __restrict__ y2b,
                                                     const bf16_t* __restrict__ w2b,
                                                     const float* __restrict__ b2,
                                                     const float* __restrict__ g4,
                                                     const float* __restrict__ x,
                                                     float* __restrict__ out) {
  const int bid = blockIdx.x;
  const int xcd = bid & 7, j = bid >> 3;
  const int mt = xcd * 8 + j / 12;
  const int ct = j % 12;
  const int tid = threadIdx.x;
  const int w = tid >> 6, l = tid & 63;
  const int lq = l >> 4, lr = l & 15;

  __shared__ __align__(16) bf16_t lA[128 * 64];
  __shared__ __align__(16) bf16_t lB[128 * 64];

  f32x4 acc[2][4][2] = {};
  const int mwave = (w & 1) * 64, nwave = (w >> 1) * 32;
  const int crow = l >> 3;
  const int cbg = (l & 7) ^ (crow & 7);

  for (int k0 = 0; k0 < FC2_IN; k0 += 64) {
#pragma unroll
    for (int i = 0; i < 4; i++) {
      int c = w * 4 + i;
      int row = c * 8 + crow;
      async_copy16(y2b + (size_t)(mt * 128 + row) * FC2_IN + k0 + cbg * 8, lA + c * 512);
      int grow = ((row >> 6) * 768) + ct * 64 + (row & 63);
      async_copy16(w2b + (size_t)grow * FC2_IN + k0 + cbg * 8, lB + c * 512);
    }
    __syncthreads();
#pragma unroll
    for (int ks = 0; ks < 2; ks++) {
      const int cbA = ((ks * 4 + lq) ^ (lr & 7)) * 8;
      bf16x8 af[4], bfr[2][2];
#pragma unroll
      for (int mi = 0; mi < 4; mi++)
        af[mi] = *(const bf16x8*)(lA + (mwave + mi * 16 + lr) * 64 + cbA);
#pragma unroll
      for (int h = 0; h < 2; h++)
#pragma unroll
        for (int ni = 0; ni < 2; ni++)
          bfr[h][ni] = *(const bf16x8*)(lB + (h * 64 + nwave + ni * 16 + lr) * 64 + cbA);
#pragma unroll
      for (int h = 0; h < 2; h++)
#pragma unroll
        for (int mi = 0; mi < 4; mi++)
#pragma unroll
          for (int ni = 0; ni < 2; ni++)
            acc[h][mi][ni] = __builtin_amdgcn_mfma_f32_16x16x32_bf16(af[mi], bfr[h][ni], acc[h][mi][ni], 0, 0, 0);
    }
    __syncthreads();
  }

#pragma unroll
  for (int mi = 0; mi < 4; mi++) {
    int row0 = mt * 128 + mwave + mi * 16 + lq * 4;
    float4 G[4];
#pragma unroll
    for (int r = 0; r < 4; r++) G[r] = ((const float4*)g4)[row0 + r];
#pragma unroll
    for (int ni = 0; ni < 2; ni++) {
      int col = ct * 64 + nwave + ni * 16 + lr;
      float b20 = b2[col], b21 = b2[768 + col];
#pragma unroll
      for (int r = 0; r < 4; r++) {
        float gw = (col < 96) ? G[r].x : (col < 192) ? G[r].y : (col < 384) ? G[r].z : G[r].w;
        float o = (acc[0][mi][ni][r] + b20) + (acc[1][mi][ni][r] + b21);
        size_t idx = (size_t)(row0 + r) * DIM + col;
        out[idx] = x[idx] + gw * o;
      }
    }
  }
}

extern "C" void kernel_launch(void* const* d_in, const int* in_sizes, int n_in,
                              void* d_out, int out_size, void* d_ws, size_t ws_size,
                              hipStream_t stream) {
  const float* x     = (const float*)d_in[0];
  const float* wr    = (const float*)d_in[1];
  const float* gamma = (const float*)d_in[2];
  const float* beta  = (const float*)d_in[3];
  const float* w1    = (const float*)d_in[4];
  const float* b1    = (const float*)d_in[5];
  const float* w2    = (const float*)d_in[6];
  const float* b2    = (const float*)d_in[7];
  float* out = (float*)d_out;

  char* ws = (char*)d_ws;
  float*  probs    = (float*)(ws + 0);            // 131072
  float*  gate_tok = (float*)(ws + 131072);       // 131072
  float*  cntf     = (float*)(ws + 262144);       // 32768
  float*  g4       = (float*)(ws + 294912);       // 131072
  bf16_t* w1b      = (bf16_t*)(ws + 425984);      // 8257536
  bf16_t* w2b      = (bf16_t*)(ws + 8683520);     // 11796480
  bf16_t* ytil     = (bf16_t*)(ws + 20480000);    // 12582912
  bf16_t* y2b      = (bf16_t*)(ws + 33062912);    // 62914560
  bf16_t* qb       = (bf16_t*)(ws + 95977472);    // 12582912
  bf16_t* kb       = (bf16_t*)(ws + 108560384);   // 12582912
  bf16_t* vtb      = (bf16_t*)(ws + 121143296);   // 12582912

  cast_router_kernel<<<4096, 256, 0, stream>>>(w1, w2, w1b, w2b, x, wr, probs);
  rank_kernel<<<dim3(4, 32), 256, 0, stream>>>(probs, gate_tok);
  ln_kernel<<<2048, 256, 0, stream>>>(x, gamma, beta, gate_tok, ytil, cntf, g4);
  fc1_kernel<<<2688, 256, 0, stream>>>(ytil, w1b, b1, cntf, y2b, qb, kb, vtb);
  attn_kernel<<<768, 256, 0, stream>>>(qb, kb, vtb, y2b);
  fc2_kernel<<<768, 256, 0, stream>>>(y2b, w2b, b2, g4, x, out);
}